// Round 17
// baseline (856.882 us; speedup 1.0000x reference)
//
#include <hip/hip_runtime.h>
#include <hip/hip_bf16.h>
#include <math.h>

#define T_   64
#define B_   2048
#define OBS_ 48
#define H_   256
#define M1_  512
#define M2_  256
#define A_   12
#define BH_  (B_ * H_)
#define KP_  320   // padded K for scan: 64 (x) + 128 (own h) + 128 (partner h)
#define GROUPS_  128  // row groups (16 rows each)
#define SLICES_  2    // column-slice blocks per group (128 h-cols each)
#define RPB_     16   // rows per block
#define NSCAN_   (GROUPS_ * SLICES_)   // 256 scan blocks, interleaved in bids 0..511
#define NMLP_    ((T_ * B_) / 64)      // 2048 MLP blocks

typedef unsigned short u16;
typedef unsigned long long u64;
typedef __attribute__((ext_vector_type(8))) short bf16x8;
typedef __attribute__((ext_vector_type(4))) float f32x4;

static __device__ __forceinline__ u16 f2b(float f) {
    __hip_bfloat16 h = __float2bfloat16(f);
    return *reinterpret_cast<u16*>(&h);
}
static __device__ __forceinline__ float b2f(u16 u) {
    union { unsigned u32v; float f; } v; v.u32v = ((unsigned)u) << 16; return v.f;
}
static __device__ __forceinline__ float sigm(float x) {
    return 1.0f / (1.0f + __expf(-x));
}
static __device__ __forceinline__ float tanh_fast(float x) {
    x = fminf(fmaxf(x, -15.0f), 15.0f);
    float e = __expf(2.0f * x);
    return (e - 1.0f) / (e + 1.0f);
}
static __device__ __forceinline__ float elu(float x) {
    return x > 0.0f ? x : (__expf(x) - 1.0f);
}

// ---------------------------------------------------------------------------
// Unified pre-pass (one dispatch): blocks 0..4095 = xpad; 4096..5919 = weights.
// Wcat: r7's per-slice K-permutation:
//   k 0..63 = x | 64..191 = own h-half | 192..319 = partner h-half
// row = ((s*8 + w)*4 + g)*16 + jj  <-  src gate-row g*256 + s*128 + w*16 + jj
// ---------------------------------------------------------------------------
__global__ void prep_all(const float* __restrict__ x, u16* __restrict__ xpad,
                         const float* __restrict__ W_ih, const float* __restrict__ W_hh,
                         const float* __restrict__ W1,  const float* __restrict__ W2,
                         const float* __restrict__ Wm,  const float* __restrict__ Ws,
                         u16* __restrict__ Wcat, u16* __restrict__ W1T,
                         u16* __restrict__ W2T,  u16* __restrict__ WhT,
                         unsigned* __restrict__ cnt) {
    const int blk = blockIdx.x, tid = threadIdx.x;
    if (blk < 4096) {
        const int gid = blk * 256 + tid;              // T*B*8 threads exactly
        const int r = gid >> 3, k0 = (gid & 7) * 8;
        u16 tmp[8];
        if (k0 < OBS_) {
            const float4 f0 = *(const float4*)(x + (size_t)r * OBS_ + k0);
            const float4 f1 = *(const float4*)(x + (size_t)r * OBS_ + k0 + 4);
            tmp[0] = f2b(f0.x); tmp[1] = f2b(f0.y); tmp[2] = f2b(f0.z); tmp[3] = f2b(f0.w);
            tmp[4] = f2b(f1.x); tmp[5] = f2b(f1.y); tmp[6] = f2b(f1.z); tmp[7] = f2b(f1.w);
        } else {
            #pragma unroll
            for (int i = 0; i < 8; ++i) tmp[i] = 0;
        }
        *(uint4*)(xpad + (size_t)gid * 8) = *(uint4*)tmp;
        return;
    }
    const int b = blk - 4096;                         // 0..1823
    if (b == 0 && tid < NSCAN_) cnt[tid] = 0;
    if (b < 1024) {
        const int s = b >> 9, w = (b >> 6) & 7, g = (b >> 4) & 3, jj = b & 15;
        const int src = g * 256 + s * 128 + w * 16 + jj;
        for (int k = tid; k < KP_; k += 256) {
            float v;
            if (k < OBS_)     v = W_ih[src * OBS_ + k];
            else if (k < 64)  v = 0.0f;
            else if (k < 192) v = W_hh[src * H_ + s * 128 + (k - 64)];        // own half
            else              v = W_hh[src * H_ + (1 - s) * 128 + (k - 192)]; // partner half
            Wcat[b * KP_ + k] = f2b(v);
        }
    } else if (b < 1536) {
        const int n = b - 1024;                       // W1T [512][256]
        W1T[n * 256 + tid] = f2b(W1[tid * M1_ + n]);
    } else if (b < 1792) {
        const int n = b - 1536;                       // W2T [256][512]
        W2T[n * 512 + tid]       = f2b(W2[tid * M2_ + n]);
        W2T[n * 512 + tid + 256] = f2b(W2[(tid + 256) * M2_ + n]);
    } else {
        const int n = b - 1792;                       // WhT [32][256]
        float v = 0.0f;
        if (n < 12)                 v = Wm[tid * A_ + n];
        else if (n >= 16 && n < 28) v = Ws[tid * A_ + (n - 16)];
        WhT[n * 256 + tid] = f2b(v);
    }
}

// ---------------------------------------------------------------------------
// FUSED scan + MLP (round 17): r15 roles VERBATIM; placement fixed with a
// HEAD-CONFINED period-16 interleave.
//   scan  iff bid < 512 && (bid & 8) == 0;   sid  = (bid>>4)*8 + (bid&7)
//   MLP head (bid<512, bid&8):               mbid = (bid>>4)*8 + (bid&7)
//   MLP tail (bid>=512):                     mbid = 256 + (bid - 512)
// Why: the CP is in-order with XCD = bid%8 and fill-to-capacity per CU
// (r15 evidence: scan-first packed scan 2/CU on half the machine). With
// 8-scan/8-MLP alternation per 16 bids, each XCD's block sequence alternates
// scan/MLP, so every CU gets 1 scan + 1 MLP. All 256 scan blocks sit in the
// initial ~512-block resident window (r16's deadlock came from scattering
// them across the whole grid -> dependency inversion -> guard breaks).
// ---------------------------------------------------------------------------
#define ASM_(row, chunk) (a_sm + (size_t)(row) * 320 + (size_t)(((chunk) ^ ((row) & 7)) << 3))
#define SY(row, col) ((size_t)(row) * 256 + ((((col) >> 3) ^ ((row) & 7)) << 3) + ((col) & 7))

__global__ __launch_bounds__(512, 2) void scan_mlp(
    const u16*  __restrict__ xpad,   // [T][B][64] bf16
    const int*  __restrict__ done,   // [T][B]
    const float* __restrict__ h0,    // [B][256] fp32
    const float* __restrict__ c0,    // [B][256] fp32
    u16*        __restrict__ hs,     // [T+1][B][256] bf16; slices 1..T written
    const u16*  __restrict__ Wcat,   // [1024 permuted][320] bf16
    const float* __restrict__ b_ih,
    const float* __restrict__ b_hh,
    unsigned*   __restrict__ cnt,    // [256] per-slice step flags (zeroed by prep)
    float*      __restrict__ out,    // [T*B][14]
    const float* __restrict__ lng, const float* __restrict__ lnb,
    const u16*  __restrict__ W1T, const float* __restrict__ b1,
    const u16*  __restrict__ W2T, const float* __restrict__ b2,
    const u16*  __restrict__ WhT,
    const float* __restrict__ bm, const float* __restrict__ bs)
{
    __shared__ u16 smem[32768];      // 64 KB: scan uses 10 KB; MLP uses all
    __shared__ unsigned okf;

    const int tid  = threadIdx.x;
    const int lane = tid & 63;
    const int quad = (lane >> 4), l16 = lane & 15;
    const int bid  = blockIdx.x;
    const bool is_scan = (bid < 512) && ((bid & 8) == 0);

    if (is_scan) {
        // ================= SCAN ROLE (r7 verbatim) =================
        u16* a_sm = smem;
        const int sid  = (bid >> 4) * 8 + (bid & 7); // scan slice id 0..255
        const int w    = tid >> 6;               // wave 0..7 -> h-colfrag
        const int grp  = sid >> 1;               // 0..127
        const int s    = sid & 1;                // 0..1
        const int psid = sid ^ 1;                // partner slice id
        const int b0   = grp * RPB_;
        const int j    = s * 128 + w * 16 + l16; // this lane's h column
        const int jrel = w * 16 + l16;           // own-relative column
        const int pc0  = (1 - s) * 128;          // partner column base

        float bsum[4];
        #pragma unroll
        for (int g = 0; g < 4; ++g) bsum[g] = b_ih[g * 256 + j] + b_hh[g * 256 + j];

        float cst[4];
        #pragma unroll
        for (int r = 0; r < 4; ++r) {
            const int row = b0 + quad * 4 + r;
            cst[r] = done[row] ? 0.0f : c0[(size_t)row * H_ + j];
        }

        // weight slice, register-resident: 4 gates x 10 kt (all static idx)
        bf16x8 Bs[4][10];
        #pragma unroll
        for (int g = 0; g < 4; ++g) {
            const u16* wp = Wcat + (size_t)(((s * 8 + w) * 4 + g) * 16 + l16) * KP_ + quad * 8;
            #pragma unroll
            for (int kt = 0; kt < 10; ++kt)
                Bs[g][kt] = *(const bf16x8*)(wp + kt * 32);
        }

        // pre-loop staging: x(0) + full h0 (masked, permuted)
        if ((tid & 3) == 0) {
            const int idx = tid >> 2, row = idx >> 3, seg = idx & 7;
            *(uint4*)ASM_(row, seg) =
                *(const uint4*)(xpad + (size_t)(b0 + row) * 64 + seg * 8);
        }
        {
            const int row = tid >> 5, c8 = tid & 31;
            const int cglob = c8 * 8;
            const int dn = done[b0 + row];
            const float* hr = h0 + (size_t)(b0 + row) * H_ + cglob;
            u16 tmp[8];
            #pragma unroll
            for (int e = 0; e < 8; ++e) tmp[e] = dn ? (u16)0 : f2b(hr[e]);
            const int chunk = (((cglob >> 7) == s) ? 8 : 24) + ((cglob & 127) >> 3);
            *(uint4*)ASM_(row, chunk) = *(uint4*)tmp;
        }
        __syncthreads();

        for (int t = 0; t < T_; ++t) {
            // prefetch partner flag (consumed after part A)
            unsigned fv = 0;
            if (tid == 0 && t > 0)
                fv = __hip_atomic_load(&cnt[psid], __ATOMIC_RELAXED,
                                       __HIP_MEMORY_SCOPE_AGENT);

            // part A: x + own half, kt 0..5 = 24 MFMA
            f32x4 acc[4];
            #pragma unroll
            for (int g = 0; g < 4; ++g) acc[g] = (f32x4){0, 0, 0, 0};
            #pragma unroll
            for (int kt = 0; kt < 6; ++kt) {
                const bf16x8 af = *(const bf16x8*)ASM_(l16, kt * 4 + quad);
                #pragma unroll
                for (int g = 0; g < 4; ++g)
                    acc[g] = __builtin_amdgcn_mfma_f32_16x16x32_bf16(af, Bs[g][kt], acc[g], 0, 0, 0);
            }

            // confirm partner flag (steady state: no spin, one barrier)
            if (tid == 0) okf = (t == 0 || fv >= (unsigned)t) ? 1u : 0u;
            __syncthreads();
            {
                int guard = 0;
                while (!okf) {
                    if (tid == 0) {
                        __builtin_amdgcn_s_sleep(1);
                        fv = __hip_atomic_load(&cnt[psid], __ATOMIC_RELAXED,
                                               __HIP_MEMORY_SCOPE_AGENT);
                        if (fv >= (unsigned)t || ++guard > (1 << 22)) okf = 1u;
                    }
                    __syncthreads();
                }
            }

            // stage partner-h(t) (thr 0..255, chunks 24..39) || x(t+1)
            if (t > 0 && tid < 256) {
                const u16* hst = hs + (size_t)t * BH_;
                const int row = tid >> 4, q = tid & 15;
                const int dn = done[(size_t)t * B_ + b0 + row];
                uint4 hv = *(const uint4*)(hst + (size_t)(b0 + row) * H_ + pc0 + q * 8);
                if (dn) hv = make_uint4(0u, 0u, 0u, 0u);
                *(uint4*)ASM_(row, 24 + q) = hv;
            }
            if (t + 1 < T_ && tid >= 256 && tid < 384) {
                const int idx = tid - 256, row = idx >> 3, seg = idx & 7;
                *(uint4*)ASM_(row, seg) =
                    *(const uint4*)(xpad + ((size_t)(t + 1) * B_ + b0 + row) * 64 + seg * 8);
            }
            __syncthreads();

            // part B: partner half, kt 6..9 = 16 MFMA
            #pragma unroll
            for (int kt = 6; kt < 10; ++kt) {
                const bf16x8 af = *(const bf16x8*)ASM_(l16, kt * 4 + quad);
                #pragma unroll
                for (int g = 0; g < 4; ++g)
                    acc[g] = __builtin_amdgcn_mfma_f32_16x16x32_bf16(af, Bs[g][kt], acc[g], 0, 0, 0);
            }

            // epilogue (no barrier: writes own chunks 8..23 only)
            u16* hs1 = hs + (size_t)(t + 1) * BH_;
            #pragma unroll
            for (int r = 0; r < 4; ++r) {
                const int rowl = quad * 4 + r;
                const int rowg = b0 + rowl;
                const float gi = acc[0][r] + bsum[0];
                const float gf = acc[1][r] + bsum[1];
                const float gg = acc[2][r] + bsum[2];
                const float go = acc[3][r] + bsum[3];
                const float cn = sigm(gf) * cst[r] + sigm(gi) * tanh_fast(gg);
                const float h  = sigm(go) * tanh_fast(cn);
                const float kp = (t + 1 < T_)
                    ? (done[(size_t)(t + 1) * B_ + rowg] ? 0.0f : 1.0f) : 1.0f;
                cst[r] = cn * kp;                      // pre-mask c for step t+1
                const int e = 64 + jrel;               // own half into LDS
                *(ASM_(rowl, e >> 3) + (e & 7)) = f2b(h * kp);
                const unsigned hb = (unsigned)f2b(h);  // unmasked history
                const unsigned ob = (unsigned)__shfl_xor((int)hb, 1);
                if ((l16 & 1) == 0) {                  // pack (j, j+1) -> u32
                    const unsigned val = hb | (ob << 16);
                    __hip_atomic_store((unsigned*)(hs1 + (size_t)rowg * H_ + (j & ~1)), val,
                                       __ATOMIC_RELAXED, __HIP_MEMORY_SCOPE_AGENT);
                }
            }
            __syncthreads();   // drains vmcnt (sc1 stores visible) + LDS order

            // post flag EVERY step (incl. last) - MLP consumers need it
            if (tid == 0)
                __hip_atomic_store(&cnt[sid], (unsigned)(t + 1),
                                   __ATOMIC_RELAXED, __HIP_MEMORY_SCOPE_AGENT);
        }
        return;
    }

    // ================= MLP ROLE (r7 verbatim + entry poll) =================
    u16* ybf = smem;                 // 32 KB
    u16* yh  = smem + 16384;         // 32 KB
    const int wave = tid >> 6;       // 0..7
    const int mbid = (bid < 512) ? ((bid >> 4) * 8 + (bid & 7))   // head MLP
                                 : (256 + (bid - 512));           // tail MLP
    const int row0 = mbid * 64;      // global row in [0, T*B)
    const u16* hsr = hs + BH_;       // slice-1-based view

    // ---- wait until hs slice (1 + row0/B_) rows [row0%B, +64) are published ----
    {
        const int ts = row0 / B_ + 1;            // required cnt value
        const int g0 = (row0 % B_) / RPB_;       // 4 consecutive groups
        if (tid < 8) {
            const int grp = g0 + (tid >> 1), s = tid & 1;
            int guard = 0;
            while (__hip_atomic_load(&cnt[grp * 2 + s], __ATOMIC_RELAXED,
                                     __HIP_MEMORY_SCOPE_AGENT) < (unsigned)ts) {
                __builtin_amdgcn_s_sleep(2);
                if (++guard > (1 << 22)) break;  // pathology -> wrong answer, not hang
            }
        }
        __syncthreads();
    }

    // ---- LayerNorm: wave w -> rows w*8..w*8+7; lane holds 4 cols ----
    {
        const float4 gv = *(const float4*)(lng + lane * 4);
        const float4 bv = *(const float4*)(lnb + lane * 4);
        #pragma unroll
        for (int rr = 0; rr < 8; ++rr) {
            const int r = wave * 8 + rr;
            const u64 hv8 = __builtin_nontemporal_load(
                (const u64*)(hsr + (size_t)(row0 + r) * H_ + lane * 4));
            const u16 h0v = (u16)(hv8 & 0xffff), h1v = (u16)((hv8 >> 16) & 0xffff);
            const u16 h2v = (u16)((hv8 >> 32) & 0xffff), h3v = (u16)(hv8 >> 48);
            const float v0 = b2f(h0v), v1 = b2f(h1v), v2 = b2f(h2v), v3 = b2f(h3v);
            float s  = v0 + v1 + v2 + v3;
            float ss = v0 * v0 + v1 * v1 + v2 * v2 + v3 * v3;
            #pragma unroll
            for (int off = 32; off > 0; off >>= 1) {
                s  += __shfl_down(s,  off);
                ss += __shfl_down(ss, off);
            }
            s = __shfl(s, 0); ss = __shfl(ss, 0);
            const float mu   = s * (1.0f / 256.0f);
            const float rstd = rsqrtf(ss * (1.0f / 256.0f) - mu * mu + 1e-5f);
            ushort4 o;
            o.x = f2b((v0 - mu) * rstd * gv.x + bv.x);
            o.y = f2b((v1 - mu) * rstd * gv.y + bv.y);
            o.z = f2b((v2 - mu) * rstd * gv.z + bv.z);
            o.w = f2b((v3 - mu) * rstd * gv.w + bv.w);
            *(ushort4*)(ybf + SY(r, lane * 4)) = o;
        }
    }
    __syncthreads();

    // ---- L2 partial accumulators across both phases ----
    f32x4 acc2[4][2];
    #pragma unroll
    for (int m = 0; m < 4; ++m)
        #pragma unroll
        for (int jj = 0; jj < 2; ++jj) acc2[m][jj] = (f32x4){0,0,0,0};

    #pragma unroll
    for (int ph = 0; ph < 2; ++ph) {
        {
            f32x4 acc[4][2];
            #pragma unroll
            for (int m = 0; m < 4; ++m)
                #pragma unroll
                for (int jj = 0; jj < 2; ++jj) acc[m][jj] = (f32x4){0,0,0,0};
            const int n0 = ph * 256 + wave * 32;
            const u16* wp0 = W1T + (size_t)(n0 + l16) * 256 + quad * 8;
            const u16* wp1 = W1T + (size_t)(n0 + 16 + l16) * 256 + quad * 8;
            #pragma unroll
            for (int kt = 0; kt < 8; ++kt) {
                const int k0 = kt * 32;
                const bf16x8 bw0 = *(const bf16x8*)(wp0 + k0);
                const bf16x8 bw1 = *(const bf16x8*)(wp1 + k0);
                #pragma unroll
                for (int m = 0; m < 4; ++m) {
                    const bf16x8 af = *(const bf16x8*)(ybf + SY(m * 16 + l16, k0 + quad * 8));
                    acc[m][0] = __builtin_amdgcn_mfma_f32_16x16x32_bf16(af, bw0, acc[m][0], 0, 0, 0);
                    acc[m][1] = __builtin_amdgcn_mfma_f32_16x16x32_bf16(af, bw1, acc[m][1], 0, 0, 0);
                }
            }
            const float bb0 = b1[n0 + l16], bb1 = b1[n0 + 16 + l16];
            __syncthreads();   // yh free
            #pragma unroll
            for (int m = 0; m < 4; ++m)
                #pragma unroll
                for (int r = 0; r < 4; ++r) {
                    const int row = m * 16 + quad * 4 + r;
                    yh[SY(row, wave * 32 + l16)]      = f2b(elu(acc[m][0][r] + bb0));
                    yh[SY(row, wave * 32 + 16 + l16)] = f2b(elu(acc[m][1][r] + bb1));
                }
        }
        __syncthreads();

        {
            const int n0 = wave * 32;
            const u16* wp0 = W2T + (size_t)(n0 + l16) * 512 + ph * 256 + quad * 8;
            const u16* wp1 = W2T + (size_t)(n0 + 16 + l16) * 512 + ph * 256 + quad * 8;
            #pragma unroll
            for (int kt = 0; kt < 8; ++kt) {
                const int k0 = kt * 32;
                const bf16x8 bw0 = *(const bf16x8*)(wp0 + k0);
                const bf16x8 bw1 = *(const bf16x8*)(wp1 + k0);
                #pragma unroll
                for (int m = 0; m < 4; ++m) {
                    const bf16x8 af = *(const bf16x8*)(yh + SY(m * 16 + l16, k0 + quad * 8));
                    acc2[m][0] = __builtin_amdgcn_mfma_f32_16x16x32_bf16(af, bw0, acc2[m][0], 0, 0, 0);
                    acc2[m][1] = __builtin_amdgcn_mfma_f32_16x16x32_bf16(af, bw1, acc2[m][1], 0, 0, 0);
                }
            }
        }
        __syncthreads();
    }

    // ---- y2 = elu(acc2 + b2) -> ybf ----
    {
        const float bb0 = b2[wave * 32 + l16], bb1 = b2[wave * 32 + 16 + l16];
        #pragma unroll
        for (int m = 0; m < 4; ++m)
            #pragma unroll
            for (int r = 0; r < 4; ++r) {
                const int row = m * 16 + quad * 4 + r;
                ybf[SY(row, wave * 32 + l16)]      = f2b(elu(acc2[m][0][r] + bb0));
                ybf[SY(row, wave * 32 + 16 + l16)] = f2b(elu(acc2[m][1][r] + bb1));
            }
    }
    __syncthreads();

    // ---- Heads ----
    float* lsf = (float*)yh;   // overlay: [64][16] floats
    if (wave < 4) {
        f32x4 a0 = {0,0,0,0}, a1 = {0,0,0,0};
        const u16* wp0 = WhT + (size_t)l16 * 256 + quad * 8;          // mean
        const u16* wp1 = WhT + (size_t)(16 + l16) * 256 + quad * 8;   // logstd
        #pragma unroll
        for (int kt = 0; kt < 8; ++kt) {
            const int k0 = kt * 32;
            const bf16x8 af  = *(const bf16x8*)(ybf + SY(wave * 16 + l16, k0 + quad * 8));
            const bf16x8 bw0 = *(const bf16x8*)(wp0 + k0);
            const bf16x8 bw1 = *(const bf16x8*)(wp1 + k0);
            a0 = __builtin_amdgcn_mfma_f32_16x16x32_bf16(af, bw0, a0, 0, 0, 0);
            a1 = __builtin_amdgcn_mfma_f32_16x16x32_bf16(af, bw1, a1, 0, 0, 0);
        }
        if (l16 < 12) {
            const float bbm = bm[l16], bbs = bs[l16];
            #pragma unroll
            for (int r = 0; r < 4; ++r) {
                const int row = wave * 16 + quad * 4 + r;
                out[(size_t)(row0 + row) * 14 + l16] = a0[r] + bbm;
                lsf[row * 16 + l16] = fminf(fmaxf(a1[r] + bbs, -5.0f), 2.0f);
            }
        }
    }
    __syncthreads();
    if (tid < 64) {
        float s = 0.0f;
        #pragma unroll
        for (int q = 0; q < 12; ++q) s += lsf[tid * 16 + q];
        const float LOG2PI = 1.8378770664093453f;
        out[(size_t)(row0 + tid) * 14 + 12] = -s - 6.0f * LOG2PI;
        out[(size_t)(row0 + tid) * 14 + 13] =  s + 6.0f + 6.0f * LOG2PI;
    }
}

// ---------------------------------------------------------------------------
extern "C" void kernel_launch(void* const* d_in, const int* in_sizes, int n_in,
                              void* d_out, int out_size, void* d_ws, size_t ws_size,
                              hipStream_t stream) {
    (void)in_sizes; (void)n_in; (void)out_size; (void)ws_size;
    const float* x    = (const float*)d_in[0];
    const int*   done = (const int*)  d_in[1];
    const float* h0   = (const float*)d_in[2];
    const float* c0   = (const float*)d_in[3];
    const float* W_ih = (const float*)d_in[4];
    const float* W_hh = (const float*)d_in[5];
    const float* b_ih = (const float*)d_in[6];
    const float* b_hh = (const float*)d_in[7];
    const float* lng  = (const float*)d_in[8];
    const float* lnb  = (const float*)d_in[9];
    const float* W1   = (const float*)d_in[10];
    const float* b1   = (const float*)d_in[11];
    const float* W2   = (const float*)d_in[12];
    const float* b2   = (const float*)d_in[13];
    const float* Wm   = (const float*)d_in[14];
    const float* bm   = (const float*)d_in[15];
    const float* Ws   = (const float*)d_in[16];
    const float* bs   = (const float*)d_in[17];
    float* out = (float*)d_out;

    // workspace carve (~52 MB; ws_size >= 135 MB confirmed)
    unsigned char* p = (unsigned char*)d_ws;
    u16* hs    = (u16*)p;              p += (size_t)(T_ + 1) * BH_ * 2;
    u16* xpad  = (u16*)p;              p += (size_t)T_ * B_ * 64 * 2;
    u16* Wcat  = (u16*)p;              p += (size_t)1024 * KP_ * 2;
    u16* W1T   = (u16*)p;              p += (size_t)M1_ * H_ * 2;
    u16* W2T   = (u16*)p;              p += (size_t)M2_ * M1_ * 2;
    u16* WhT   = (u16*)p;              p += (size_t)32 * H_ * 2;
    unsigned* cnt = (unsigned*)p;      p += 1024;

    prep_all<<<4096 + 1824, 256, 0, stream>>>(x, xpad, W_ih, W_hh, W1, W2, Wm, Ws,
                                              Wcat, W1T, W2T, WhT, cnt);

    scan_mlp<<<512 + (NMLP_ - 256), 512, 0, stream>>>(
        xpad, done, h0, c0, hs, Wcat, b_ih, b_hh, cnt,
        out, lng, lnb, W1T, b1, W2T, b2, WhT, bm, bs);
}